// Round 1
// 110.522 us; speedup vs baseline: 1.4061x; 1.4061x over previous
//
#include <hip/hip_runtime.h>
#include <hip/hip_bf16.h>

#define DD 512
#define NN 8
#define LL0 128
#define LL1 256

// 2 * log2(e): pre-scale factor so tanh(t) can use v_exp_f32 (2^x) directly.
#define LOG2E2 2.8853900817779268f

__device__ __forceinline__ float fexp2(float x) {
#if __has_builtin(__builtin_amdgcn_exp2f)
    return __builtin_amdgcn_exp2f(x);
#else
    float r; asm("v_exp_f32 %0, %1" : "=v"(r) : "v"(x)); return r;
#endif
}
__device__ __forceinline__ float frcp(float x) {
#if __has_builtin(__builtin_amdgcn_rcpf)
    return __builtin_amdgcn_rcpf(x);
#else
    float r; asm("v_rcp_f32 %0, %1" : "=v"(r) : "v"(x)); return r;
#endif
}

// sigma2(t2) = 1/(2^t2 + 1), where t2 = 2*log2e*t.  tanh(t) = 1 - 2*sigma2.
__device__ __forceinline__ float sig2(float t2) {
    return frcp(fexp2(t2) + 1.0f);
}

// ---------------------------------------------------------------------------
// Kernel 1: fused projections (unchanged GEMM, new epilogue).
// xpb[row,e] = 2log2e * (x.Wx + Wb)   ;   mp[row,e] = 2log2e * (m.Wm)
// ---------------------------------------------------------------------------
__global__ __launch_bounds__(256) void proj_kernel(
    const float* __restrict__ x, const float* __restrict__ m,
    const float* __restrict__ W, const float* __restrict__ Wb,
    float* __restrict__ xpb, float* __restrict__ mp)
{
    __shared__ float As[64][17];
    __shared__ float Bs[64][17];

    int row0 = blockIdx.x * 64;
    int e0   = blockIdx.y * 64;
    bool isx = row0 < (NN * LL0);
    const float* A = isx ? (x + (size_t)row0 * DD)
                         : (m + (size_t)(row0 - NN * LL0) * DD);
    int koff = isx ? 0 : DD;
    float* outp = isx ? (xpb + (size_t)row0 * DD)
                      : (mp + (size_t)(row0 - NN * LL0) * DD);

    int tid = threadIdx.x;
    int lr = tid >> 2;            // 0..63
    int lc = (tid & 3) * 4;       // 0,4,8,12
    int ty = tid >> 4, tx = tid & 15;

    float acc[4][4] = {};
    for (int k0 = 0; k0 < DD; k0 += 16) {
        float4 av = *(const float4*)(A + (size_t)lr * DD + k0 + lc);
        float4 wv = *(const float4*)(W + (size_t)(e0 + lr) * (2 * DD) + koff + k0 + lc);
        As[lr][lc + 0] = av.x; As[lr][lc + 1] = av.y;
        As[lr][lc + 2] = av.z; As[lr][lc + 3] = av.w;
        Bs[lr][lc + 0] = wv.x; Bs[lr][lc + 1] = wv.y;
        Bs[lr][lc + 2] = wv.z; Bs[lr][lc + 3] = wv.w;
        __syncthreads();
        #pragma unroll
        for (int kk = 0; kk < 16; ++kk) {
            float a_[4], b_[4];
            #pragma unroll
            for (int i = 0; i < 4; ++i) a_[i] = As[ty * 4 + i][kk];
            #pragma unroll
            for (int j = 0; j < 4; ++j) b_[j] = Bs[tx * 4 + j][kk];
            #pragma unroll
            for (int i = 0; i < 4; ++i)
                #pragma unroll
                for (int j = 0; j < 4; ++j)
                    acc[i][j] = fmaf(a_[i], b_[j], acc[i][j]);
        }
        __syncthreads();
    }
    #pragma unroll
    for (int i = 0; i < 4; ++i) {
        #pragma unroll
        for (int j = 0; j < 4; ++j) {
            int e = e0 + tx * 4 + j;
            float v = acc[i][j];
            if (isx) v += Wb[e];
            outp[(size_t)(ty * 4 + i) * DD + e] = v * LOG2E2;
        }
    }
}

// ---------------------------------------------------------------------------
// Kernel 2: logits partials.
//   wpart[dc][n][a][b] = sum_{d in chunk dc} V[d] / (2^(xpb[n,a,d]+mp[n,b,d]) + 1)
// Final logit (up to a global additive const dropped by softmax) = -2 * sum_dc.
// Tile: 32a x 32b per block, 2x2 per thread (rows r and r+16), d-chunk = 128.
// Grid: (bt=8, at*4|dc=16, n=8) = 1024 blocks, 256 threads.
// ---------------------------------------------------------------------------
__global__ __launch_bounds__(256) void logits_kernel(
    const float* __restrict__ xpb, const float* __restrict__ mp,
    const float* __restrict__ Vw,
    float* __restrict__ wpart)
{
    __shared__ __attribute__((aligned(16))) float xs[32][132];
    __shared__ __attribute__((aligned(16))) float ms[32][132];
    __shared__ __attribute__((aligned(16))) float vsh[128];

    int n  = blockIdx.z;
    int bt = blockIdx.x;          // 0..7
    int at = blockIdx.y & 3;      // 0..3
    int dc = blockIdx.y >> 2;     // 0..3 (d-chunk of 128)
    int tid = threadIdx.x;
    int ty = tid >> 4, tx = tid & 15;

    const float* xrow = xpb + (size_t)(n * LL0 + at * 32) * DD + dc * 128;
    const float* mrow = mp  + (size_t)(n * LL1 + bt * 32) * DD + dc * 128;

    // stage 32x128 of x-proj and m-proj
    {
        int sr = tid >> 5;            // 0..7
        int sc = (tid & 31) * 4;      // 0..124
        #pragma unroll
        for (int i = 0; i < 4; ++i) {
            int r = sr + i * 8;
            *(float4*)&xs[r][sc] = *(const float4*)(xrow + (size_t)r * DD + sc);
            *(float4*)&ms[r][sc] = *(const float4*)(mrow + (size_t)r * DD + sc);
        }
        if (tid < 32)
            *(float4*)&vsh[tid * 4] = *(const float4*)(Vw + dc * 128 + tid * 4);
    }
    __syncthreads();

    float a00 = 0.f, a01 = 0.f, a10 = 0.f, a11 = 0.f;

    #pragma unroll 4
    for (int k4 = 0; k4 < 32; ++k4) {
        float4 xa = *(const float4*)&xs[ty][k4 * 4];
        float4 xb = *(const float4*)&xs[ty + 16][k4 * 4];
        float4 ma = *(const float4*)&ms[tx][k4 * 4];
        float4 mb = *(const float4*)&ms[tx + 16][k4 * 4];
        float4 vv = *(const float4*)&vsh[k4 * 4];

        a00 = fmaf(vv.x, sig2(xa.x + ma.x), a00);
        a00 = fmaf(vv.y, sig2(xa.y + ma.y), a00);
        a00 = fmaf(vv.z, sig2(xa.z + ma.z), a00);
        a00 = fmaf(vv.w, sig2(xa.w + ma.w), a00);

        a01 = fmaf(vv.x, sig2(xa.x + mb.x), a01);
        a01 = fmaf(vv.y, sig2(xa.y + mb.y), a01);
        a01 = fmaf(vv.z, sig2(xa.z + mb.z), a01);
        a01 = fmaf(vv.w, sig2(xa.w + mb.w), a01);

        a10 = fmaf(vv.x, sig2(xb.x + ma.x), a10);
        a10 = fmaf(vv.y, sig2(xb.y + ma.y), a10);
        a10 = fmaf(vv.z, sig2(xb.z + ma.z), a10);
        a10 = fmaf(vv.w, sig2(xb.w + ma.w), a10);

        a11 = fmaf(vv.x, sig2(xb.x + mb.x), a11);
        a11 = fmaf(vv.y, sig2(xb.y + mb.y), a11);
        a11 = fmaf(vv.z, sig2(xb.z + mb.z), a11);
        a11 = fmaf(vv.w, sig2(xb.w + mb.w), a11);
    }

    float* wp = wpart + ((size_t)dc * NN + n) * (size_t)(LL0 * LL1);
    int a = at * 32 + ty;
    int b = bt * 32 + tx;
    wp[(size_t)a * LL1 + b]             = a00;
    wp[(size_t)a * LL1 + b + 16]        = a01;
    wp[(size_t)(a + 16) * LL1 + b]      = a10;
    wp[(size_t)(a + 16) * LL1 + b + 16] = a11;
}

// ---------------------------------------------------------------------------
// Kernel 3: masked softmax over b. Sums the 4 d-chunk partials, applies the
// -2 scale (the +const term of tanh cancels under softmax shift-invariance),
// writes the softmax result into plane 0 of wpart (= wbuf).
// ---------------------------------------------------------------------------
__global__ __launch_bounds__(256) void softmax_kernel(
    float* __restrict__ wbuf, const int* __restrict__ mask)
{
    __shared__ float red[4];
    __shared__ float red2[4];
    const size_t P = (size_t)NN * LL0 * LL1;
    int row = blockIdx.x;          // n*L0 + a
    int n = row >> 7;
    int b = threadIdx.x;
    size_t idx = (size_t)row * LL1 + b;

    float s4 = wbuf[idx] + wbuf[idx + P] + wbuf[idx + 2 * P] + wbuf[idx + 3 * P];
    float w = -2.0f * s4;
    if (mask[n * LL1 + b] == 0) w = -1e12f;

    float mx = w;
    #pragma unroll
    for (int off = 32; off; off >>= 1) mx = fmaxf(mx, __shfl_xor(mx, off));
    int wv = threadIdx.x >> 6;
    if ((threadIdx.x & 63) == 0) red[wv] = mx;
    __syncthreads();
    mx = fmaxf(fmaxf(red[0], red[1]), fmaxf(red[2], red[3]));

    float e = __expf(w - mx);
    float s = e;
    #pragma unroll
    for (int off = 32; off; off >>= 1) s += __shfl_xor(s, off);
    if ((threadIdx.x & 63) == 0) red2[wv] = s;
    __syncthreads();
    s = red2[0] + red2[1] + red2[2] + red2[3];

    wbuf[idx] = e / s;
}

// ---------------------------------------------------------------------------
// Kernel 4: v[n,a,d] = sum_b w[n,a,b] * m[n,b,d]. (unchanged)
// ---------------------------------------------------------------------------
__global__ __launch_bounds__(256) void vgemm_kernel(
    const float* __restrict__ wbuf, const float* __restrict__ m,
    float* __restrict__ out)
{
    __shared__ float ws_t[64][17];
    __shared__ float ms_t[16][65];

    int n = blockIdx.z;
    int a0 = blockIdx.y * 64;
    int d0 = blockIdx.x * 64;
    int tid = threadIdx.x;
    int ty = tid >> 4, tx = tid & 15;

    const float* wrow = wbuf + ((size_t)n * LL0 + a0) * LL1;
    const float* mrow = m + (size_t)n * LL1 * DD;

    float acc[4][4] = {};
    for (int k0 = 0; k0 < LL1; k0 += 16) {
        {
            int lr = tid >> 2, lc = (tid & 3) * 4;
            float4 wv = *(const float4*)(wrow + (size_t)lr * LL1 + k0 + lc);
            ws_t[lr][lc + 0] = wv.x; ws_t[lr][lc + 1] = wv.y;
            ws_t[lr][lc + 2] = wv.z; ws_t[lr][lc + 3] = wv.w;
        }
        {
            int lr = tid >> 4, lc = (tid & 15) * 4;
            float4 mv = *(const float4*)(mrow + (size_t)(k0 + lr) * DD + d0 + lc);
            ms_t[lr][lc + 0] = mv.x; ms_t[lr][lc + 1] = mv.y;
            ms_t[lr][lc + 2] = mv.z; ms_t[lr][lc + 3] = mv.w;
        }
        __syncthreads();
        #pragma unroll
        for (int kk = 0; kk < 16; ++kk) {
            float a_[4], b_[4];
            #pragma unroll
            for (int i = 0; i < 4; ++i) a_[i] = ws_t[ty * 4 + i][kk];
            #pragma unroll
            for (int j = 0; j < 4; ++j) b_[j] = ms_t[kk][tx * 4 + j];
            #pragma unroll
            for (int i = 0; i < 4; ++i)
                #pragma unroll
                for (int j = 0; j < 4; ++j)
                    acc[i][j] = fmaf(a_[i], b_[j], acc[i][j]);
        }
        __syncthreads();
    }
    #pragma unroll
    for (int i = 0; i < 4; ++i)
        #pragma unroll
        for (int j = 0; j < 4; ++j)
            out[((size_t)n * LL0 + a0 + ty * 4 + i) * DD + d0 + tx * 4 + j] = acc[i][j];
}

extern "C" void kernel_launch(void* const* d_in, const int* in_sizes, int n_in,
                              void* d_out, int out_size, void* d_ws, size_t ws_size,
                              hipStream_t stream) {
    const float* x    = (const float*)d_in[0];
    const float* m    = (const float*)d_in[1];
    const int*   mask = (const int*)d_in[2];
    const float* W_w  = (const float*)d_in[3];
    const float* W_b  = (const float*)d_in[4];
    const float* V_w  = (const float*)d_in[5];
    const float* V_b  = (const float*)d_in[6];
    (void)V_b; // additive constant — cancels under softmax shift-invariance
    float* out = (float*)d_out;

    float* xpb   = (float*)d_ws;                      // 8*128*512  = 524288 f
    float* mp    = xpb + (size_t)NN * LL0 * DD;       // 8*256*512  = 1048576 f
    float* wpart = mp + (size_t)NN * LL1 * DD;        // 4*8*128*256 = 1048576 f
    // total workspace: 2,621,440 floats = 10 MB

    proj_kernel<<<dim3(48, 8), 256, 0, stream>>>(x, m, W_w, W_b, xpb, mp);
    logits_kernel<<<dim3(8, 16, 8), 256, 0, stream>>>(xpb, mp, V_w, wpart);
    softmax_kernel<<<dim3(1024), 256, 0, stream>>>(wpart, mask);
    vgemm_kernel<<<dim3(8, 2, 8), 256, 0, stream>>>(wpart, m, out);
}

// Round 2
// 84.329 us; speedup vs baseline: 1.8428x; 1.3106x over previous
//
#include <hip/hip_runtime.h>
#include <hip/hip_bf16.h>

#define DD 512
#define NN 8
#define LL0 128
#define LL1 256

// 2 * log2(e): pre-scale factor so tanh(t) can use v_exp_f32 (2^x) directly.
#define LOG2E2 2.8853900817779268f

// split-K partial plane stride (floats): 3072 rows x 512 e
#define PSTR ((size_t)3072 * 512)

__device__ __forceinline__ float fexp2(float x) {
#if __has_builtin(__builtin_amdgcn_exp2f)
    return __builtin_amdgcn_exp2f(x);
#else
    float r; asm("v_exp_f32 %0, %1" : "=v"(r) : "v"(x)); return r;
#endif
}
__device__ __forceinline__ float frcp(float x) {
#if __has_builtin(__builtin_amdgcn_rcpf)
    return __builtin_amdgcn_rcpf(x);
#else
    float r; asm("v_rcp_f32 %0, %1" : "=v"(r) : "v"(x)); return r;
#endif
}

// sigma2(t2) = 1/(2^t2 + 1), where t2 = 2*log2e*t.  tanh(t) = 1 - 2*sigma2.
__device__ __forceinline__ float sig2(float t2) {
    return frcp(fexp2(t2) + 1.0f);
}

// ---------------------------------------------------------------------------
// Kernel 1: fused projections, split-K=2.
// pp[kz][row][e] = sum_{k in half kz} A[row,k] * W[e, koff+k]
//   rows [0,1024)  : A = x, koff = 0
//   rows [1024,3072): A = m, koff = 512
// Tile 64(M) x 64(e), K-chunk 32, 256 threads, 4x4 micro-tile.
// LDS tiles stored TRANSPOSED [k][row] (pad 68) -> inner loop reads are
// 2x ds_read_b128 per kk (a: 4-addr broadcast, b: 2-way-free).
// Grid (48, 8, 2) = 768 blocks = 3/CU.
// ---------------------------------------------------------------------------
__global__ __launch_bounds__(256, 3) void proj_kernel(
    const float* __restrict__ x, const float* __restrict__ m,
    const float* __restrict__ W, float* __restrict__ pp)
{
    __shared__ float At[32][68];   // [k][row], 68*4=272B row stride (16B aligned)
    __shared__ float Bt[32][68];   // [k][e]

    int row0 = blockIdx.x * 64;
    int e0   = blockIdx.y * 64;
    int kb   = blockIdx.z * 256;   // K-half base

    bool isx = row0 < (NN * LL0);
    const float* A  = (isx ? x + (size_t)row0 * DD
                           : m + (size_t)(row0 - NN * LL0) * DD) + kb;
    const float* Wp = W + (size_t)e0 * (2 * DD) + (isx ? 0 : DD) + kb;

    int t  = threadIdx.x;
    int lr = t >> 2;              // 0..63 : staging row (A) / e-row (B)
    int kc = (t & 3) * 8;         // 0,8,16,24 : k-offset within 32-chunk
    int ty = t >> 4, tx = t & 15; // micro-tile: rows ty*4..+3, cols tx*4..+3

    const float* Ap = A  + (size_t)lr * DD + kc;
    const float* Bp = Wp + (size_t)lr * (2 * DD) + kc;

    // prefetch K-tile 0 into registers
    float4 ar0 = *(const float4*)(Ap);
    float4 ar1 = *(const float4*)(Ap + 4);
    float4 br0 = *(const float4*)(Bp);
    float4 br1 = *(const float4*)(Bp + 4);

    float acc[4][4] = {};

    for (int kt = 0; kt < 8; ++kt) {
        if (kt) __syncthreads();       // previous tile's reads complete
        // registers -> LDS, transposed
        At[kc + 0][lr] = ar0.x; At[kc + 1][lr] = ar0.y;
        At[kc + 2][lr] = ar0.z; At[kc + 3][lr] = ar0.w;
        At[kc + 4][lr] = ar1.x; At[kc + 5][lr] = ar1.y;
        At[kc + 6][lr] = ar1.z; At[kc + 7][lr] = ar1.w;
        Bt[kc + 0][lr] = br0.x; Bt[kc + 1][lr] = br0.y;
        Bt[kc + 2][lr] = br0.z; Bt[kc + 3][lr] = br0.w;
        Bt[kc + 4][lr] = br1.x; Bt[kc + 5][lr] = br1.y;
        Bt[kc + 6][lr] = br1.z; Bt[kc + 7][lr] = br1.w;
        if (kt < 7) {                  // issue next tile's loads (hide under compute)
            int ko = (kt + 1) * 32;
            ar0 = *(const float4*)(Ap + ko);
            ar1 = *(const float4*)(Ap + ko + 4);
            br0 = *(const float4*)(Bp + ko);
            br1 = *(const float4*)(Bp + ko + 4);
        }
        __syncthreads();               // LDS writes visible

        #pragma unroll
        for (int kk = 0; kk < 32; ++kk) {
            float4 av = *(const float4*)&At[kk][ty * 4];
            float4 bv = *(const float4*)&Bt[kk][tx * 4];
            acc[0][0] = fmaf(av.x, bv.x, acc[0][0]);
            acc[0][1] = fmaf(av.x, bv.y, acc[0][1]);
            acc[0][2] = fmaf(av.x, bv.z, acc[0][2]);
            acc[0][3] = fmaf(av.x, bv.w, acc[0][3]);
            acc[1][0] = fmaf(av.y, bv.x, acc[1][0]);
            acc[1][1] = fmaf(av.y, bv.y, acc[1][1]);
            acc[1][2] = fmaf(av.y, bv.z, acc[1][2]);
            acc[1][3] = fmaf(av.y, bv.w, acc[1][3]);
            acc[2][0] = fmaf(av.z, bv.x, acc[2][0]);
            acc[2][1] = fmaf(av.z, bv.y, acc[2][1]);
            acc[2][2] = fmaf(av.z, bv.z, acc[2][2]);
            acc[2][3] = fmaf(av.z, bv.w, acc[2][3]);
            acc[3][0] = fmaf(av.w, bv.x, acc[3][0]);
            acc[3][1] = fmaf(av.w, bv.y, acc[3][1]);
            acc[3][2] = fmaf(av.w, bv.z, acc[3][2]);
            acc[3][3] = fmaf(av.w, bv.w, acc[3][3]);
        }
    }

    float* outp = pp + (size_t)blockIdx.z * PSTR
                     + (size_t)row0 * DD + e0 + tx * 4;
    #pragma unroll
    for (int i = 0; i < 4; ++i) {
        float4 v = make_float4(acc[i][0], acc[i][1], acc[i][2], acc[i][3]);
        *(float4*)(outp + (size_t)(ty * 4 + i) * DD) = v;
    }
}

// ---------------------------------------------------------------------------
// Kernel 1b: split-K reduce + bias + LOG2E2 scale.
// xpb_base[row][e] = LOG2E2 * (pp[0]+pp[1] + (row<1024 ? Wb[e] : 0))
// xpb_base is the contiguous xpb|mp region (1024 x-rows then 2048 m-rows).
// ---------------------------------------------------------------------------
__global__ __launch_bounds__(256) void reduce_kernel(
    const float* __restrict__ pp, const float* __restrict__ Wb,
    float* __restrict__ xpb_base)
{
    size_t f = (size_t)blockIdx.x * 256 + threadIdx.x;   // float4 index
    const float4* p4 = (const float4*)pp;
    float4 v0 = p4[f];
    float4 v1 = p4[f + PSTR / 4];
    float4 s = make_float4(v0.x + v1.x, v0.y + v1.y, v0.z + v1.z, v0.w + v1.w);
    size_t off = f * 4;
    if (off < (size_t)NN * LL0 * DD) {   // x-rows: add bias
        float4 wb = *(const float4*)(Wb + (off & (DD - 1)));
        s.x += wb.x; s.y += wb.y; s.z += wb.z; s.w += wb.w;
    }
    s.x *= LOG2E2; s.y *= LOG2E2; s.z *= LOG2E2; s.w *= LOG2E2;
    ((float4*)xpb_base)[f] = s;
}

// ---------------------------------------------------------------------------
// Kernel 2: logits partials. (unchanged)
//   wpart[dc][n][a][b] = sum_{d in chunk dc} V[d] / (2^(xpb[n,a,d]+mp[n,b,d]) + 1)
// ---------------------------------------------------------------------------
__global__ __launch_bounds__(256) void logits_kernel(
    const float* __restrict__ xpb, const float* __restrict__ mp,
    const float* __restrict__ Vw,
    float* __restrict__ wpart)
{
    __shared__ __attribute__((aligned(16))) float xs[32][132];
    __shared__ __attribute__((aligned(16))) float ms[32][132];
    __shared__ __attribute__((aligned(16))) float vsh[128];

    int n  = blockIdx.z;
    int bt = blockIdx.x;          // 0..7
    int at = blockIdx.y & 3;      // 0..3
    int dc = blockIdx.y >> 2;     // 0..3 (d-chunk of 128)
    int tid = threadIdx.x;
    int ty = tid >> 4, tx = tid & 15;

    const float* xrow = xpb + (size_t)(n * LL0 + at * 32) * DD + dc * 128;
    const float* mrow = mp  + (size_t)(n * LL1 + bt * 32) * DD + dc * 128;

    {
        int sr = tid >> 5;            // 0..7
        int sc = (tid & 31) * 4;      // 0..124
        #pragma unroll
        for (int i = 0; i < 4; ++i) {
            int r = sr + i * 8;
            *(float4*)&xs[r][sc] = *(const float4*)(xrow + (size_t)r * DD + sc);
            *(float4*)&ms[r][sc] = *(const float4*)(mrow + (size_t)r * DD + sc);
        }
        if (tid < 32)
            *(float4*)&vsh[tid * 4] = *(const float4*)(Vw + dc * 128 + tid * 4);
    }
    __syncthreads();

    float a00 = 0.f, a01 = 0.f, a10 = 0.f, a11 = 0.f;

    #pragma unroll 4
    for (int k4 = 0; k4 < 32; ++k4) {
        float4 xa = *(const float4*)&xs[ty][k4 * 4];
        float4 xb = *(const float4*)&xs[ty + 16][k4 * 4];
        float4 ma = *(const float4*)&ms[tx][k4 * 4];
        float4 mb = *(const float4*)&ms[tx + 16][k4 * 4];
        float4 vv = *(const float4*)&vsh[k4 * 4];

        a00 = fmaf(vv.x, sig2(xa.x + ma.x), a00);
        a00 = fmaf(vv.y, sig2(xa.y + ma.y), a00);
        a00 = fmaf(vv.z, sig2(xa.z + ma.z), a00);
        a00 = fmaf(vv.w, sig2(xa.w + ma.w), a00);

        a01 = fmaf(vv.x, sig2(xa.x + mb.x), a01);
        a01 = fmaf(vv.y, sig2(xa.y + mb.y), a01);
        a01 = fmaf(vv.z, sig2(xa.z + mb.z), a01);
        a01 = fmaf(vv.w, sig2(xa.w + mb.w), a01);

        a10 = fmaf(vv.x, sig2(xb.x + ma.x), a10);
        a10 = fmaf(vv.y, sig2(xb.y + ma.y), a10);
        a10 = fmaf(vv.z, sig2(xb.z + ma.z), a10);
        a10 = fmaf(vv.w, sig2(xb.w + ma.w), a10);

        a11 = fmaf(vv.x, sig2(xb.x + mb.x), a11);
        a11 = fmaf(vv.y, sig2(xb.y + mb.y), a11);
        a11 = fmaf(vv.z, sig2(xb.z + mb.z), a11);
        a11 = fmaf(vv.w, sig2(xb.w + mb.w), a11);
    }

    float* wp = wpart + ((size_t)dc * NN + n) * (size_t)(LL0 * LL1);
    int a = at * 32 + ty;
    int b = bt * 32 + tx;
    wp[(size_t)a * LL1 + b]             = a00;
    wp[(size_t)a * LL1 + b + 16]        = a01;
    wp[(size_t)(a + 16) * LL1 + b]      = a10;
    wp[(size_t)(a + 16) * LL1 + b + 16] = a11;
}

// ---------------------------------------------------------------------------
// Kernel 3: masked softmax over b (sums 4 d-chunk partials, -2 scale).
// ---------------------------------------------------------------------------
__global__ __launch_bounds__(256) void softmax_kernel(
    float* __restrict__ wbuf, const int* __restrict__ mask)
{
    __shared__ float red[4];
    __shared__ float red2[4];
    const size_t P = (size_t)NN * LL0 * LL1;
    int row = blockIdx.x;          // n*L0 + a
    int n = row >> 7;
    int b = threadIdx.x;
    size_t idx = (size_t)row * LL1 + b;

    float s4 = wbuf[idx] + wbuf[idx + P] + wbuf[idx + 2 * P] + wbuf[idx + 3 * P];
    float w = -2.0f * s4;
    if (mask[n * LL1 + b] == 0) w = -1e12f;

    float mx = w;
    #pragma unroll
    for (int off = 32; off; off >>= 1) mx = fmaxf(mx, __shfl_xor(mx, off));
    int wv = threadIdx.x >> 6;
    if ((threadIdx.x & 63) == 0) red[wv] = mx;
    __syncthreads();
    mx = fmaxf(fmaxf(red[0], red[1]), fmaxf(red[2], red[3]));

    float e = __expf(w - mx);
    float s = e;
    #pragma unroll
    for (int off = 32; off; off >>= 1) s += __shfl_xor(s, off);
    if ((threadIdx.x & 63) == 0) red2[wv] = s;
    __syncthreads();
    s = red2[0] + red2[1] + red2[2] + red2[3];

    wbuf[idx] = e / s;
}

// ---------------------------------------------------------------------------
// Kernel 4: v[n,a,d] = sum_b w[n,a,b] * m[n,b,d]. (unchanged)
// ---------------------------------------------------------------------------
__global__ __launch_bounds__(256) void vgemm_kernel(
    const float* __restrict__ wbuf, const float* __restrict__ m,
    float* __restrict__ out)
{
    __shared__ float ws_t[64][17];
    __shared__ float ms_t[16][65];

    int n = blockIdx.z;
    int a0 = blockIdx.y * 64;
    int d0 = blockIdx.x * 64;
    int tid = threadIdx.x;
    int ty = tid >> 4, tx = tid & 15;

    const float* wrow = wbuf + ((size_t)n * LL0 + a0) * LL1;
    const float* mrow = m + (size_t)n * LL1 * DD;

    float acc[4][4] = {};
    for (int k0 = 0; k0 < LL1; k0 += 16) {
        {
            int lr = tid >> 2, lc = (tid & 3) * 4;
            float4 wv = *(const float4*)(wrow + (size_t)lr * LL1 + k0 + lc);
            ws_t[lr][lc + 0] = wv.x; ws_t[lr][lc + 1] = wv.y;
            ws_t[lr][lc + 2] = wv.z; ws_t[lr][lc + 3] = wv.w;
        }
        {
            int lr = tid >> 4, lc = (tid & 15) * 4;
            float4 mv = *(const float4*)(mrow + (size_t)(k0 + lr) * DD + d0 + lc);
            ms_t[lr][lc + 0] = mv.x; ms_t[lr][lc + 1] = mv.y;
            ms_t[lr][lc + 2] = mv.z; ms_t[lr][lc + 3] = mv.w;
        }
        __syncthreads();
        #pragma unroll
        for (int kk = 0; kk < 16; ++kk) {
            float a_[4], b_[4];
            #pragma unroll
            for (int i = 0; i < 4; ++i) a_[i] = ws_t[ty * 4 + i][kk];
            #pragma unroll
            for (int j = 0; j < 4; ++j) b_[j] = ms_t[kk][tx * 4 + j];
            #pragma unroll
            for (int i = 0; i < 4; ++i)
                #pragma unroll
                for (int j = 0; j < 4; ++j)
                    acc[i][j] = fmaf(a_[i], b_[j], acc[i][j]);
        }
        __syncthreads();
    }
    #pragma unroll
    for (int i = 0; i < 4; ++i)
        #pragma unroll
        for (int j = 0; j < 4; ++j)
            out[((size_t)n * LL0 + a0 + ty * 4 + i) * DD + d0 + tx * 4 + j] = acc[i][j];
}

extern "C" void kernel_launch(void* const* d_in, const int* in_sizes, int n_in,
                              void* d_out, int out_size, void* d_ws, size_t ws_size,
                              hipStream_t stream) {
    const float* x    = (const float*)d_in[0];
    const float* m    = (const float*)d_in[1];
    const int*   mask = (const int*)d_in[2];
    const float* W_w  = (const float*)d_in[3];
    const float* W_b  = (const float*)d_in[4];
    const float* V_w  = (const float*)d_in[5];
    const float* V_b  = (const float*)d_in[6];
    (void)V_b; // additive constant — cancels under softmax shift-invariance
    float* out = (float*)d_out;

    // Workspace layout (floats):
    //   xpb   : 8*128*512          =  524288   (x-projection, scaled)
    //   mp    : 8*256*512          = 1048576   (m-projection, scaled; contiguous after xpb)
    //   region: max(pp 2*3072*512 = 3145728, wpart 4*8*128*256 = 1048576)
    // pp (split-K partials) is dead after reduce_kernel; wpart aliases it.
    // Total: 4,718,592 floats = 18.9 MB
    float* xpb   = (float*)d_ws;
    float* mp    = xpb + (size_t)NN * LL0 * DD;
    float* region = mp + (size_t)NN * LL1 * DD;
    float* pp    = region;
    float* wpart = region;

    proj_kernel<<<dim3(48, 8, 2), 256, 0, stream>>>(x, m, W_w, pp);
    reduce_kernel<<<dim3(1536), 256, 0, stream>>>(pp, W_b, xpb);
    logits_kernel<<<dim3(8, 16, 8), 256, 0, stream>>>(xpb, mp, V_w, wpart);
    softmax_kernel<<<dim3(1024), 256, 0, stream>>>(wpart, mask);
    vgemm_kernel<<<dim3(8, 2, 8), 256, 0, stream>>>(wpart, m, out);
}